// Round 10
// baseline (1060.280 us; speedup 1.0000x reference)
//
#include <hip/hip_runtime.h>
#include <hip/hip_bf16.h>

#define NB 32
#define NS 2048
#define DIM 1024
#define NM (NB*NS)   // 65536 rows
#define CAP 256      // max rescored rows per batch
#define SEL_MARGIN 24.0f

typedef __attribute__((ext_vector_type(8))) short short8;
typedef __attribute__((ext_vector_type(4))) float f32x4;
typedef __attribute__((ext_vector_type(4))) unsigned short us16x4;
typedef unsigned short us16;
typedef unsigned int   u32;
typedef __attribute__((address_space(3))) void lds_void;
typedef __attribute__((address_space(1))) void glb_void;

__device__ __forceinline__ void gload16(const void* g, void* l){
  __builtin_amdgcn_global_load_lds((const glb_void*)g, (lds_void*)l, 16, 0, 0);
}

__device__ __forceinline__ float fast_tanh(float x){
  float e = __builtin_exp2f(x * 2.8853900817779268f); // e^{2x}
  return 1.0f - 2.0f/(e + 1.0f);
}

__device__ __forceinline__ void split_bf16(float x, short &hi, short &lo){
  u32 u = __float_as_uint(x);
  float hf = __uint_as_float(u & 0xFFFF0000u);
  hi = (short)(u >> 16);
  lo = (short)(__float_as_uint(x - hf) >> 16);
}

// ---------------- fused prep: wb images + avec + sel_count zero ---------------
__global__ void k_prep(const float* __restrict__ wb,
                       const float* __restrict__ kin,
                       const float* __restrict__ wa,
                       char* __restrict__ imgf,
                       char* __restrict__ img1,
                       float* __restrict__ avec,
                       int* __restrict__ sel_count){
  __shared__ float4 kl[256];
  const int h = blockIdx.x, t = threadIdx.x;
  if(h == 0 && t < NB) sel_count[t] = 0;
  if(h < 1024){
    // phase-2 B image: 16B slot = ((kt*64 + ct16)*2 + hl)*64 + lane
    const int tid = h*256 + t;
    const int kt   = tid >> 13;
    const int ct16 = (tid >> 7) & 63;
    const int hl   = (tid >> 6) & 1;
    const int lane = tid & 63;
    const int col  = ct16*16 + (lane & 15);
    const int k0   = kt*32 + (lane >> 4)*8;
    const float* src = wb + (size_t)col*DIM + k0;
    float4 v0 = *(const float4*)src;
    float4 v1 = *(const float4*)(src + 4);
    float fv[8] = {v0.x,v0.y,v0.z,v0.w,v1.x,v1.y,v1.z,v1.w};
    short8 out;
    #pragma unroll
    for(int j=0;j<8;j++){
      short hi,lo; split_bf16(fv[j],hi,lo);
      out[j] = hl ? lo : hi;
    }
    *(short8*)(imgf + (size_t)tid*16) = out;
  } else if(h < 1536){
    // phase-1 B image = [kt(32)][cb(4)][16KB]; byte B: row=B>>7, inner=B&127,
    // ix = inner ^ ((row&7)<<4): col = cb*256 + (ix>>6)*128 + row,
    // k = kt*32 + ((ix>>4)&3)*8 + (B&15)/2 (hi bf16)
    const int tid = (h-1024)*256 + t;
    const int tile = tid >> 10;
    const int kt = tile >> 2, cb = tile & 3;
    const int byt = (tid & 1023) * 16;
    const int row = byt >> 7, inner = byt & 127;
    const int ix = inner ^ ((row & 7) << 4);
    const int colhi = ix >> 6, lkk = (ix >> 4) & 3;
    const int col = cb*256 + colhi*128 + row;
    const float* src = wb + (size_t)col*DIM + kt*32 + lkk*8;
    float4 v0 = *(const float4*)src;
    float4 v1 = *(const float4*)(src + 4);
    float fv[8] = {v0.x,v0.y,v0.z,v0.w,v1.x,v1.y,v1.z,v1.w};
    short8 out;
    #pragma unroll
    for(int j=0;j<8;j++) out[j] = (short)(__float_as_uint(fv[j]) >> 16);
    *(short8*)(img1 + (size_t)tid*16) = out;
  } else {
    const int hb = h - 1536;
    const int b = hb >> 2, oc = hb & 3;
    kl[t] = *(const float4*)(kin + b*DIM + t*4);
    __syncthreads();
    const int o = oc*256 + t;
    const float4* wrow = (const float4*)(wa + (size_t)o*DIM);
    float acc = 0.f;
    for(int i=0;i<256;i++){
      float4 wv = wrow[i]; float4 kk = kl[i];
      acc += wv.x*kk.x + wv.y*kk.y + wv.z*kk.z + wv.w*kk.w;
    }
    avec[b*DIM + o] = acc;
  }
}

// truncate-store A tile (16 f32 in AR0..AR3) into buffer DST (R7-verified layout)
#define SPLIT_STORE_A(DST, AR0,AR1,AR2,AR3)                                     \
  {                                                                             \
    float fv[16];                                                               \
    *(float4*)(fv+0)=AR0; *(float4*)(fv+4)=AR1;                                 \
    *(float4*)(fv+8)=AR2; *(float4*)(fv+12)=AR3;                                \
    short8 h0, h1;                                                              \
    _Pragma("unroll")                                                           \
    for(int j=0;j<8;j++){ h0[j] = (short)(__float_as_uint(fv[j])>>16);          \
                          h1[j] = (short)(__float_as_uint(fv[8+j])>>16); }      \
    char* abase = (DST) + sr*80;                                                \
    const int swz = (sr & 3) << 4;                                              \
    *(short8*)(abase + ((sh*32     ) ^ swz)) = h0;                              \
    *(short8*)(abase + ((sh*32 + 16) ^ swz)) = h1;                              \
  }

// one kt: read tile KT from buffers [CUR]; stage kt+1 into [1-CUR];
// ASx = A(kt+1) regs (split now); ANx = A(kt+2) destination regs.
#define BODY(KT, CUR, AS0,AS1,AS2,AS3, AN0,AN1,AN2,AN3)                         \
  {                                                                             \
    if((KT) < 31){                                                              \
      const char* gs = bsrc + (size_t)(((KT)+1)*4 + cb)*16384 + t*16;           \
      char* ld = (char*)&Bbuf[1-(CUR)][0][0] + t*16;                            \
      _Pragma("unroll")                                                         \
      for(int c=0;c<4;c++) gload16(gs + c*4096, ld + c*4096);                   \
      SPLIT_STORE_A((char*)&Abuf[1-(CUR)][0][0], AS0,AS1,AS2,AS3);              \
    }                                                                           \
    if((KT) < 30){                                                              \
      const float* a2 = ap + ((KT)+2)*32;                                       \
      AN0 = *(const float4*)(a2+0);  AN1 = *(const float4*)(a2+4);              \
      AN2 = *(const float4*)(a2+8);  AN3 = *(const float4*)(a2+12);             \
    }                                                                           \
    {                                                                           \
      short8 fa[4], fb[8];                                                      \
      const char* ar_ = (const char*)&Abuf[CUR][0][0] + a_ro;                   \
      const char* bb_ = (const char*)&Bbuf[CUR][0][0] + b_ro;                   \
      _Pragma("unroll")                                                         \
      for(int m=0;m<4;m++) fa[m] = *(const short8*)(ar_ + m*1280);              \
      _Pragma("unroll")                                                         \
      for(int n=0;n<8;n++) fb[n] = *(const short8*)(bb_ + n*2048);              \
      asm volatile("s_waitcnt lgkmcnt(0)" ::: "memory");                        \
      __builtin_amdgcn_sched_barrier(0);                                        \
      __builtin_amdgcn_s_setprio(1);                                            \
      _Pragma("unroll")                                                         \
      for(int m=0;m<4;m++)                                                      \
        _Pragma("unroll")                                                       \
        for(int n=0;n<8;n++)                                                    \
          acc[m][n] = __builtin_amdgcn_mfma_f32_16x16x32_bf16(fa[m], fb[n], acc[m][n], 0,0,0); \
      __builtin_amdgcn_s_setprio(0);                                            \
    }                                                                           \
    if((KT) < 30) asm volatile("s_waitcnt vmcnt(4)" ::: "memory");              \
    else          asm volatile("s_waitcnt vmcnt(0)" ::: "memory");              \
    __builtin_amdgcn_sched_barrier(0);                                          \
    __builtin_amdgcn_s_barrier();                                               \
  }

// ---------------- phase-1: 1-pass truncated-bf16 GEMM, single-barrier pipeline
// 128x256 block, 4 waves (64x128). A hi-only [2][128][40] dbuf (reg->split),
// B hi-only [2][128][64] dbuf (gload_lds). ONE s_barrier per kt; staging
// executes under the MFMA cluster; counted vmcnt only.
__global__ __launch_bounds__(256,3)
void k_gemm_approx(const float* __restrict__ xs,
                   const char* __restrict__ img1,
                   const float* __restrict__ avec,
                   const float* __restrict__ energy,
                   float* __restrict__ partial){
  __shared__ us16 Abuf[2][128][40];   // 2 x 10KB
  __shared__ us16 Bbuf[2][128][64];   // 2 x 16KB

  const int h  = blockIdx.x;                  // 2048 blocks
  const int rt = (h & 7) + 8*(h >> 5);        // same-rt blocks on same XCD
  const int cb = (h >> 3) & 3;                // 256-col tile index
  const int t  = threadIdx.x;
  const int w  = t >> 6, lane = t & 63;
  const int wr = w >> 1, wc = w & 1;          // wave tile: 64 rows x 128 cols
  const int lm = lane & 15, lk = lane >> 4;
  const int sr = t >> 1, sh = t & 1;

  const float* ap = xs + (size_t)(rt*128 + sr)*DIM + sh*16;
  const char*  bsrc = img1;                   // + (kt*4+cb)*16384

  const int a_ro = (wr*64 + lm)*80 + ((lk*16) ^ ((lm&3)<<4));
  const int b_ro = lm*128 + ((wc*64 + lk*16) ^ ((lm&7)<<4));

  f32x4 acc[4][8];
  #pragma unroll
  for(int m=0;m<4;m++)
    #pragma unroll
    for(int n=0;n<8;n++) acc[m][n] = (f32x4){0.f,0.f,0.f,0.f};

  // ---- prologue: A(0)->regs, B(0) gloads, split A(0)->ab[0], A(1)->regs ----
  float4 x0 = *(const float4*)(ap+0),  x1 = *(const float4*)(ap+4);
  float4 x2 = *(const float4*)(ap+8),  x3 = *(const float4*)(ap+12);
  {
    const char* gs = bsrc + (size_t)cb*16384 + t*16;
    char* ld = (char*)&Bbuf[0][0][0] + t*16;
    #pragma unroll
    for(int c=0;c<4;c++) gload16(gs + c*4096, ld + c*4096);
  }
  SPLIT_STORE_A((char*)&Abuf[0][0][0], x0, x1, x2, x3);  // auto-waits A(0) regs
  float4 y0, y1, y2, y3;
  {
    const float* a1 = ap + 32;
    y0 = *(const float4*)(a1+0);  y1 = *(const float4*)(a1+4);
    y2 = *(const float4*)(a1+8);  y3 = *(const float4*)(a1+12);
  }
  // in flight: [B(0)x4, A(1)x4] -> drain B(0), let A(1) fly
  asm volatile("s_waitcnt vmcnt(4) lgkmcnt(0)" ::: "memory");
  __builtin_amdgcn_sched_barrier(0);
  __builtin_amdgcn_s_barrier();

  // ---- main loop: 2 kt per iteration, static buffer/reg parity ----
  for(int kt=0; kt<32; kt+=2){
    BODY(kt,   0, y0,y1,y2,y3, x0,x1,x2,x3);
    BODY(kt+1, 1, x0,x1,x2,x3, y0,y1,y2,y3);
  }

  // epilogue: partial[cb*2+wc][row] = sum_o energy*tanh(a+b) over wave's 128 cols
  const int bidx = rt >> 4;
  float av[8], ev[8];
  #pragma unroll
  for(int n=0;n<8;n++){
    const int col = cb*256 + wc*128 + n*16 + lm;
    av[n] = avec[bidx*DIM + col];
    ev[n] = energy[col];
  }
  #pragma unroll
  for(int m=0;m<4;m++){
    float rs[4];
    #pragma unroll
    for(int j=0;j<4;j++){
      float s = 0.f;
      #pragma unroll
      for(int n=0;n<8;n++) s += ev[n]*fast_tanh(av[n] + acc[m][n][j]);
      s += __shfl_xor(s,1); s += __shfl_xor(s,2);
      s += __shfl_xor(s,4); s += __shfl_xor(s,8);
      rs[j] = s;
    }
    if(lm == 0){
      float4 st = {rs[0], rs[1], rs[2], rs[3]};
      *(float4*)(partial + (size_t)(cb*2+wc)*NM + rt*128 + wr*64 + m*16 + lk*4) = st;
    }
  }
}

// ---------------- select: reduce partials, masked max, pick candidates --------
__global__ void k_select(const float* __restrict__ partial,
                         const int* __restrict__ mask,
                         float* __restrict__ scores,
                         int* __restrict__ sel_count,
                         int* __restrict__ sel_list){
  const int b = blockIdx.x, t = threadIdx.x;
  const int w = t >> 6, lane = t & 63;
  __shared__ float red[4];
  float sv[8]; int mv[8];
  float m = -3.4e38f;
  #pragma unroll
  for(int j=0;j<8;j++){
    const int i = j*256 + t;
    float s = 0.f;
    #pragma unroll
    for(int c=0;c<8;c++) s += partial[(size_t)c*NM + b*NS + i];
    sv[j] = s;
    scores[b*NS + i] = s;
    mv[j] = mask[b*NS + i];
    if(mv[j] && s > m) m = s;
  }
  #pragma unroll
  for(int off=1; off<64; off<<=1) m = fmaxf(m, __shfl_xor(m, off));
  if(lane==0) red[w] = m;
  __syncthreads();
  m = fmaxf(fmaxf(red[0],red[1]), fmaxf(red[2],red[3]));
  const float thr = m - SEL_MARGIN;
  #pragma unroll
  for(int j=0;j<8;j++){
    if(mv[j] && sv[j] > thr){
      int slot = atomicAdd(&sel_count[b], 1);
      if(slot < CAP) sel_list[b*CAP + slot] = j*256 + t;
    }
  }
}

// ---------------- phase-2: exact 3-pass rescoring of selected rows ------------
__global__ __launch_bounds__(256)
void k_phase2(const float* __restrict__ xs,
              const char* __restrict__ imgf,
              const float* __restrict__ avec,
              const float* __restrict__ energy,
              const int* __restrict__ sel_count,
              const int* __restrict__ sel_list,
              float* __restrict__ p2buf){
  __shared__ us16 A2[32][80];     // hi bytes [0,64), lo at +80, row stride 160B
  __shared__ float s2[4][32];
  const int b = blockIdx.x >> 4, cb = blockIdx.x & 15;
  const int t = threadIdx.x, w = t >> 6, lane = t & 63;
  const int lm = lane & 15, lk = lane >> 4;
  const int ct = cb*4 + w;                    // ct16 index 0..63
  const int col = ct*16 + lm;
  const float av  = avec[b*DIM + col];
  const float evv = energy[col];
  char* lds = (char*)&A2[0][0];
  const int count = min(sel_count[b], CAP);
  const int ri = t >> 3, seg = t & 7;
  // 2-bit XOR key: must stay inside the 64-byte hi field (R6 lesson)
  const int wbyte = ri*160 + ((seg*8) ^ ((ri&3)<<4));
  const char* a_rd = lds + lm*160 + ((lk*16) ^ ((lm&3)<<4));

  for(int c0 = 0; c0 < count; c0 += 32){
    const int li = c0 + ri;
    const int row = sel_list[b*CAP + min(li, count-1)];
    const float* rp = xs + ((size_t)b*NS + row)*DIM + seg*4;
    f32x4 acc[2];
    acc[0] = (f32x4){0.f,0.f,0.f,0.f};
    acc[1] = (f32x4){0.f,0.f,0.f,0.f};
    for(int kt=0; kt<32; kt++){
      __syncthreads();                        // prior kt's frag reads consumed
      float4 v = *(const float4*)(rp + kt*32);
      float fv[4] = {v.x, v.y, v.z, v.w};
      us16x4 hi, lo;
      #pragma unroll
      for(int e=0;e<4;e++){
        short a, l; split_bf16(fv[e], a, l);
        hi[e] = (us16)a; lo[e] = (us16)l;
      }
      *(us16x4*)(lds + wbyte)      = hi;
      *(us16x4*)(lds + wbyte + 80) = lo;
      __syncthreads();
      const char* fbb = imgf + ((size_t)(kt*64 + ct)*2)*1024 + lane*16;
      short8 bh = *(const short8*)(fbb);
      short8 bl = *(const short8*)(fbb + 1024);
      short8 fah[2], fal[2];
      #pragma unroll
      for(int m=0;m<2;m++){
        fah[m] = *(const short8*)(a_rd + m*2560);
        fal[m] = *(const short8*)(a_rd + m*2560 + 80);
      }
      #pragma unroll
      for(int m=0;m<2;m++)
        acc[m] = __builtin_amdgcn_mfma_f32_16x16x32_bf16(fah[m], bh, acc[m], 0,0,0);
      #pragma unroll
      for(int m=0;m<2;m++)
        acc[m] = __builtin_amdgcn_mfma_f32_16x16x32_bf16(fah[m], bl, acc[m], 0,0,0);
      #pragma unroll
      for(int m=0;m<2;m++)
        acc[m] = __builtin_amdgcn_mfma_f32_16x16x32_bf16(fal[m], bh, acc[m], 0,0,0);
    }
    float s[2][4];
    #pragma unroll
    for(int m=0;m<2;m++)
      #pragma unroll
      for(int j=0;j<4;j++){
        float v = evv * fast_tanh(av + acc[m][j]);
        v += __shfl_xor(v,1); v += __shfl_xor(v,2);
        v += __shfl_xor(v,4); v += __shfl_xor(v,8);
        s[m][j] = v;
      }
    __syncthreads();
    if(lm == 0){
      #pragma unroll
      for(int m=0;m<2;m++)
        #pragma unroll
        for(int j=0;j<4;j++) s2[w][m*16 + lk*4 + j] = s[m][j];
    }
    __syncthreads();
    if(t < 32){
      float sum = s2[0][t] + s2[1][t] + s2[2][t] + s2[3][t];
      p2buf[((size_t)b*16 + cb)*CAP + c0 + t] = sum;
    }
  }
}

// ---------------- masked softmax with fused exact-score scatter ---------------
__global__ void k_softmax(const float* __restrict__ scores,
                          const float* __restrict__ p2buf,
                          const int* __restrict__ sel_count,
                          const int* __restrict__ sel_list,
                          const int* __restrict__ mask,
                          float* __restrict__ attn){
  const int b = blockIdx.x, t = threadIdx.x;
  const int w = t >> 6, lane = t & 63;
  __shared__ float sc[NS];      // 8KB: corrected scores
  __shared__ float red[4];
  #pragma unroll
  for(int j=0;j<8;j++) sc[j*256+t] = scores[b*NS + j*256 + t];
  __syncthreads();
  const int count = min(sel_count[b], CAP);
  for(int s0 = t; s0 < count; s0 += 256){
    float s = 0.f;
    #pragma unroll
    for(int c=0;c<16;c++) s += p2buf[((size_t)b*16 + c)*CAP + s0];
    sc[sel_list[b*CAP + s0]] = s;
  }
  __syncthreads();
  float sv[8]; int mv[8];
  float m = -3.4e38f;
  #pragma unroll
  for(int j=0;j<8;j++){
    const int i = j*256 + t;
    sv[j] = sc[i];
    mv[j] = mask[b*NS + i];
    if(mv[j] && sv[j] > m) m = sv[j];
  }
  #pragma unroll
  for(int off=1; off<64; off<<=1) m = fmaxf(m, __shfl_xor(m, off));
  if(lane==0) red[w] = m;
  __syncthreads();
  m = fmaxf(fmaxf(red[0],red[1]), fmaxf(red[2],red[3]));
  __syncthreads();
  float ev[8]; float l = 0.f;
  #pragma unroll
  for(int j=0;j<8;j++){
    ev[j] = mv[j] ? __builtin_exp2f((sv[j]-m)*1.4426950408889634f) : 0.f;
    l += ev[j];
  }
  #pragma unroll
  for(int off=1; off<64; off<<=1) l += __shfl_xor(l, off);
  if(lane==0) red[w] = l;
  __syncthreads();
  l = red[0]+red[1]+red[2]+red[3];
  const float inv = 1.0f/l;
  #pragma unroll
  for(int j=0;j<8;j++) attn[b*NS + j*256 + t] = ev[j]*inv;
}

// ---------------- ctx = attn @ xs, chunked (256 blocks) ----------------
__global__ void k_ctx_partial(const float* __restrict__ attn,
                              const float* __restrict__ xs,
                              float* __restrict__ cp){
  const int b = blockIdx.x >> 3, ch = blockIdx.x & 7;
  const int t = threadIdx.x;
  __shared__ float al[256];
  al[t] = attn[b*NS + ch*256 + t];
  __syncthreads();
  float4 acc = {0.f,0.f,0.f,0.f};
  const float* base = xs + (size_t)(b*NS + ch*256)*DIM + t*4;
  for(int i=0;i<256;i++){
    float wv = al[i];                 // uniform across block
    if(wv > 1e-12f){                  // contribution < 1e-8, deterministic
      float4 x = *(const float4*)(base + (size_t)i*DIM);
      acc.x += wv*x.x; acc.y += wv*x.y; acc.z += wv*x.z; acc.w += wv*x.w;
    }
  }
  *(float4*)(cp + ((size_t)ch*NB + b)*DIM + t*4) = acc;
}

__global__ void k_ctx_reduce(const float* __restrict__ cp, float* __restrict__ ctx){
  int i = blockIdx.x*256 + threadIdx.x;
  float s = 0.f;
  #pragma unroll
  for(int ch=0; ch<8; ch++) s += cp[(size_t)ch*NB*DIM + i];
  ctx[i] = s;
}

extern "C" void kernel_launch(void* const* d_in, const int* in_sizes, int n_in,
                              void* d_out, int out_size, void* d_ws, size_t ws_size,
                              hipStream_t stream) {
  const float* kin    = (const float*)d_in[0];   // [32,1024]
  const float* xs     = (const float*)d_in[1];   // [32,2048,1024]
  const int*   mask   = (const int*)d_in[2];     // [32,2048]
  const float* wa     = (const float*)d_in[3];   // [1024,1024]
  const float* wb     = (const float*)d_in[4];   // [1024,1024]
  const float* energy = (const float*)d_in[5];   // [1024]
  float* out  = (float*)d_out;
  float* ctx  = out;            // [32,1024]
  float* attn = out + NB*DIM;   // [32,2048]

  char* ws = (char*)d_ws;
  float* partial   = (float*)(ws);                       // 2 MB    @ 0
  float* avec      = (float*)(ws + 2097152);             // 128 KB
  float* scores    = (float*)(ws + 2228224);             // 256 KB
  float* cp        = (float*)(ws + 2490368);             // 1 MB
  char*  imgf      = ws + 3538944;                       // 4 MB (frag hi/lo)
  char*  img1      = ws + 7733248;                       // 2 MB (gload hi, BK=32)
  int*   sel_count = (int*)(ws + 9830400);               // 128 B
  int*   sel_list  = (int*)(ws + 9830528);               // 32 KB
  float* p2buf     = (float*)(ws + 9863296);             // 512 KB

  k_prep       <<<1664, 256, 0, stream>>>(wb, kin, wa, imgf, img1, avec, sel_count);
  k_gemm_approx<<<2048, 256, 0, stream>>>(xs, img1, avec, energy, partial);
  k_select     <<<NB, 256, 0, stream>>>(partial, mask, scores, sel_count, sel_list);
  k_phase2     <<<512, 256, 0, stream>>>(xs, imgf, avec, energy, sel_count, sel_list, p2buf);
  k_softmax    <<<NB, 256, 0, stream>>>(scores, p2buf, sel_count, sel_list, mask, attn);
  k_ctx_partial<<<256, 256, 0, stream>>>(attn, xs, cp);
  k_ctx_reduce <<<128, 256, 0, stream>>>(cp, ctx);
}

// Round 11
// 303.147 us; speedup vs baseline: 3.4976x; 3.4976x over previous
//
#include <hip/hip_runtime.h>
#include <hip/hip_bf16.h>

#define NB 32
#define NS 2048
#define DIM 1024
#define NM (NB*NS)   // 65536 rows
#define CAP 256      // max rescored rows per batch
#define SEL_MARGIN 24.0f

typedef __attribute__((ext_vector_type(8))) short short8;
typedef __attribute__((ext_vector_type(4))) float f32x4;
typedef __attribute__((ext_vector_type(4))) unsigned short us16x4;
typedef unsigned short us16;
typedef unsigned int   u32;
typedef __attribute__((address_space(3))) void lds_void;
typedef __attribute__((address_space(1))) void glb_void;

__device__ __forceinline__ void gload16(const void* g, void* l){
  __builtin_amdgcn_global_load_lds((const glb_void*)g, (lds_void*)l, 16, 0, 0);
}

__device__ __forceinline__ float fast_tanh(float x){
  float e = __builtin_exp2f(x * 2.8853900817779268f); // e^{2x}
  return 1.0f - 2.0f/(e + 1.0f);
}

__device__ __forceinline__ void split_bf16(float x, short &hi, short &lo){
  u32 u = __float_as_uint(x);
  float hf = __uint_as_float(u & 0xFFFF0000u);
  hi = (short)(u >> 16);
  lo = (short)(__float_as_uint(x - hf) >> 16);
}

// ---------------- fused prep: wb images + avec + mask compaction --------------
// blocks 0..1023: phase-2 B image (frag-ordered hi/lo)        [verified R5-R9]
// blocks 1024..1535: phase-1 B image (pre-swizzled gload hi)  [verified R7-R9]
// blocks 1536..1663: avec = k @ Wa^T (exact f32)
// blocks 1664..1695: per-batch stable compaction of unmasked rows
__global__ void k_prep(const float* __restrict__ wb,
                       const float* __restrict__ kin,
                       const float* __restrict__ wa,
                       const int* __restrict__ mask,
                       char* __restrict__ imgf,
                       char* __restrict__ img1,
                       float* __restrict__ avec,
                       int* __restrict__ cidx,
                       int* __restrict__ cnt,
                       int* __restrict__ sel_count){
  __shared__ float4 kl[256];
  __shared__ int tc[256];
  __shared__ int tot;
  const int h = blockIdx.x, t = threadIdx.x;
  if(h == 0 && t < NB) sel_count[t] = 0;
  if(h < 1024){
    // 16B slot = ((kt*64 + ct16)*2 + hl)*64 + lane ; Wb[ct16*16+(lane&15)]
    const int tid = h*256 + t;
    const int kt   = tid >> 13;
    const int ct16 = (tid >> 7) & 63;
    const int hl   = (tid >> 6) & 1;
    const int lane = tid & 63;
    const int col  = ct16*16 + (lane & 15);
    const int k0   = kt*32 + (lane >> 4)*8;
    const float* src = wb + (size_t)col*DIM + k0;
    float4 v0 = *(const float4*)src;
    float4 v1 = *(const float4*)(src + 4);
    float fv[8] = {v0.x,v0.y,v0.z,v0.w,v1.x,v1.y,v1.z,v1.w};
    short8 out;
    #pragma unroll
    for(int j=0;j<8;j++){
      short hi,lo; split_bf16(fv[j],hi,lo);
      out[j] = hl ? lo : hi;
    }
    *(short8*)(imgf + (size_t)tid*16) = out;
  } else if(h < 1536){
    // [kt(32)][cb(4)][16KB]; byte B: row=B>>7, inner=B&127,
    // ix = inner ^ ((row&7)<<4): col = cb*256 + (ix>>6)*128 + row,
    // k = kt*32 + ((ix>>4)&3)*8 + (B&15)/2 (hi bf16)
    const int tid = (h-1024)*256 + t;
    const int tile = tid >> 10;
    const int kt = tile >> 2, cb = tile & 3;
    const int byt = (tid & 1023) * 16;
    const int row = byt >> 7, inner = byt & 127;
    const int ix = inner ^ ((row & 7) << 4);
    const int colhi = ix >> 6, lkk = (ix >> 4) & 3;
    const int col = cb*256 + colhi*128 + row;
    const float* src = wb + (size_t)col*DIM + kt*32 + lkk*8;
    float4 v0 = *(const float4*)src;
    float4 v1 = *(const float4*)(src + 4);
    float fv[8] = {v0.x,v0.y,v0.z,v0.w,v1.x,v1.y,v1.z,v1.w};
    short8 out;
    #pragma unroll
    for(int j=0;j<8;j++) out[j] = (short)(__float_as_uint(fv[j]) >> 16);
    *(short8*)(img1 + (size_t)tid*16) = out;
  } else if(h < 1664){
    const int hb = h - 1536;
    const int b = hb >> 2, oc = hb & 3;
    kl[t] = *(const float4*)(kin + b*DIM + t*4);
    __syncthreads();
    const int o = oc*256 + t;
    const float4* wrow = (const float4*)(wa + (size_t)o*DIM);
    float acc = 0.f;
    for(int i=0;i<256;i++){
      float4 wv = wrow[i]; float4 kk = kl[i];
      acc += wv.x*kk.x + wv.y*kk.y + wv.z*kk.z + wv.w*kk.w;
    }
    avec[b*DIM + o] = acc;
  } else {
    // ---- stable compaction of unmasked rows for batch b ----
    const int b = h - 1664;
    int mv[8]; int c = 0;
    #pragma unroll
    for(int e=0;e<8;e++){ mv[e] = mask[b*NS + t*8 + e]; c += (mv[e] ? 1 : 0); }
    tc[t] = c;
    __syncthreads();
    for(int d=1; d<256; d<<=1){          // Hillis-Steele inclusive scan
      int v = tc[t];
      int add = (t >= d) ? tc[t-d] : 0;
      __syncthreads();
      tc[t] = v + add;
      __syncthreads();
    }
    const int excl = tc[t] - c;
    if(t == 255) tot = tc[t];
    __syncthreads();
    int pos = excl;
    #pragma unroll
    for(int e=0;e<8;e++){
      if(mv[e]) cidx[b*NS + (pos++)] = t*8 + e;
    }
    const int total = tot;
    if(t == 0) cnt[b] = total;
    for(int p = total + t; p < NS; p += 256) cidx[b*NS + p] = 0;  // safe pad
  }
}

// ---------------- phase-1: 1-pass truncated-bf16 GEMM over COMPACTED rows -----
// R9-verified structure (2-barrier, counted vmcnt, 3 blocks/CU). Only delta:
// row gather via cidx + early-exit for tiles past the batch's unmasked count.
__global__ __launch_bounds__(256,2)
void k_gemm_approx(const float* __restrict__ xs,
                   const char* __restrict__ img1,
                   const float* __restrict__ avec,
                   const float* __restrict__ energy,
                   const int* __restrict__ cidx,
                   const int* __restrict__ cnt,
                   float* __restrict__ partial){
  __shared__ us16 Abuf[128][40];      // hi only; row stride 80B
  __shared__ us16 Bbuf[2][128][64];   // 2 x 16KB, filled by global_load_lds

  const int h  = blockIdx.x;                  // 2048 blocks
  const int rt = (h & 7) + 8*(h >> 5);        // same-rt blocks on same XCD
  const int cb = (h >> 3) & 3;                // 256-col tile index
  const int bidx = rt >> 4, tile = rt & 15;   // batch / row-tile within batch
  if(tile*128 >= cnt[bidx]) return;           // whole tile beyond unmasked count
  const int t  = threadIdx.x;
  const int w  = t >> 6, lane = t & 63;
  const int wr = w >> 1, wc = w & 1;          // wave tile: 64 rows x 128 cols
  const int lm = lane & 15, lk = lane >> 4;
  const int sr = t >> 1, sh = t & 1;

  const int orig = cidx[bidx*NS + tile*128 + sr];   // gathered source row
  const float* ap = xs + ((size_t)bidx*NS + orig)*DIM + sh*16;
  const char*  bsrc = img1;                   // + (kt*4+cb)*16384

  const char* a_rd = (const char*)&Abuf[0][0] + (wr*64 + lm)*80 + ((lk*16) ^ ((lm&3)<<4));
  const int boff = (wc*64 + lk*16) ^ ((lm&7)<<4);

  f32x4 acc[4][8];
  #pragma unroll
  for(int m=0;m<4;m++)
    #pragma unroll
    for(int n=0;n<8;n++) acc[m][n] = (f32x4){0.f,0.f,0.f,0.f};

  // prologue: A(0) regs FIRST (oldest in FIFO), then B(0) gloads
  float4 ar0 = *(const float4*)(ap+0),  ar1 = *(const float4*)(ap+4);
  float4 ar2 = *(const float4*)(ap+8),  ar3 = *(const float4*)(ap+12);
  {
    const char* gs = bsrc + (size_t)cb*16384 + t*16;
    char* ld = (char*)&Bbuf[0][0][0] + t*16;
    #pragma unroll
    for(int c=0;c<4;c++) gload16(gs + c*4096, ld + c*4096);
  }

  for(int kt=0; kt<32; kt++){
    const int cur = kt & 1;
    // bar1: all waves' frag reads of tile kt-1 done (lgkm only — NO vmem drain)
    asm volatile("s_waitcnt lgkmcnt(0)" ::: "memory");
    __builtin_amdgcn_sched_barrier(0);
    __builtin_amdgcn_s_barrier();
    {   // truncate-store A(kt) from ar
      float fv[16];
      *(float4*)(fv+0)=ar0; *(float4*)(fv+4)=ar1;
      *(float4*)(fv+8)=ar2; *(float4*)(fv+12)=ar3;
      short8 h0, h1;
      #pragma unroll
      for(int j=0;j<8;j++){ h0[j] = (short)(__float_as_uint(fv[j])>>16);
                            h1[j] = (short)(__float_as_uint(fv[8+j])>>16); }
      char* abase = (char*)&Abuf[0][0] + sr*80;
      const int swz = (sr & 3) << 4;
      *(short8*)(abase + ((sh*32     ) ^ swz)) = h0;
      *(short8*)(abase + ((sh*32 + 16) ^ swz)) = h1;
    }
    if(kt < 31){
      const float* a2 = ap + (kt+1)*32;   // A(kt+1) regs first (oldest)
      ar0 = *(const float4*)(a2+0);  ar1 = *(const float4*)(a2+4);
      ar2 = *(const float4*)(a2+8);  ar3 = *(const float4*)(a2+12);
      {                                   // then B(kt+1) gloads
        const char* gs = bsrc + (size_t)((kt+1)*4 + cb)*16384 + t*16;
        char* ld = (char*)&Bbuf[cur^1][0][0] + t*16;
        #pragma unroll
        for(int c=0;c<4;c++) gload16(gs + c*4096, ld + c*4096);
      }
      // FIFO: [B(kt)4, A(kt+1)4, B(kt+1)4] -> vmcnt(8): B(kt) landed,
      // next-tile loads stay in flight. lgkm(0) = A ds_writes visible.
      asm volatile("s_waitcnt vmcnt(8) lgkmcnt(0)" ::: "memory");
    } else {
      asm volatile("s_waitcnt vmcnt(0) lgkmcnt(0)" ::: "memory");
    }
    __builtin_amdgcn_sched_barrier(0);
    __builtin_amdgcn_s_barrier();       // bar2: tile kt fully in LDS

    short8 fa[4], fb[8];
    const char* bb = (const char*)&Bbuf[cur][0][0] + lm*128 + boff;
    #pragma unroll
    for(int m=0;m<4;m++) fa[m] = *(const short8*)(a_rd + m*1280);
    #pragma unroll
    for(int n=0;n<8;n++) fb[n] = *(const short8*)(bb + n*2048);
    #pragma unroll
    for(int m=0;m<4;m++)
      #pragma unroll
      for(int n=0;n<8;n++)
        acc[m][n] = __builtin_amdgcn_mfma_f32_16x16x32_bf16(fa[m], fb[n], acc[m][n], 0,0,0);
  }

  // epilogue: partial[cb*2+wc][compacted row] over wave's 128 cols
  float av[8], ev[8];
  #pragma unroll
  for(int n=0;n<8;n++){
    const int col = cb*256 + wc*128 + n*16 + lm;
    av[n] = avec[bidx*DIM + col];
    ev[n] = energy[col];
  }
  #pragma unroll
  for(int m=0;m<4;m++){
    float rs[4];
    #pragma unroll
    for(int j=0;j<4;j++){
      float s = 0.f;
      #pragma unroll
      for(int n=0;n<8;n++) s += ev[n]*fast_tanh(av[n] + acc[m][n][j]);
      s += __shfl_xor(s,1); s += __shfl_xor(s,2);
      s += __shfl_xor(s,4); s += __shfl_xor(s,8);
      rs[j] = s;
    }
    if(lm == 0){
      float4 st = {rs[0], rs[1], rs[2], rs[3]};
      *(float4*)(partial + (size_t)(cb*2+wc)*NM + rt*128 + wr*64 + m*16 + lk*4) = st;
    }
  }
}

// ---------------- select over compacted rows; scatter scores to orig ids ------
__global__ void k_select(const float* __restrict__ partial,
                         const int* __restrict__ cidx,
                         const int* __restrict__ cnt,
                         float* __restrict__ scores,
                         int* __restrict__ sel_count,
                         int* __restrict__ sel_list){
  const int b = blockIdx.x, t = threadIdx.x;
  const int w = t >> 6, lane = t & 63;
  __shared__ float red[4];
  const int cnt_b = cnt[b];
  float sv[8]; int orig[8];
  float m = -3.4e38f;
  #pragma unroll
  for(int j=0;j<8;j++){
    const int i = j*256 + t;                  // compacted index
    if(i < cnt_b){
      float s = 0.f;
      #pragma unroll
      for(int c=0;c<8;c++) s += partial[(size_t)c*NM + b*NS + i];
      sv[j] = s;
      orig[j] = cidx[b*NS + i];
      scores[b*NS + orig[j]] = s;             // all compacted rows are unmasked
      if(s > m) m = s;
    } else { sv[j] = -3.4e38f; orig[j] = -1; }
  }
  #pragma unroll
  for(int off=1; off<64; off<<=1) m = fmaxf(m, __shfl_xor(m, off));
  if(lane==0) red[w] = m;
  __syncthreads();
  m = fmaxf(fmaxf(red[0],red[1]), fmaxf(red[2],red[3]));
  const float thr = m - SEL_MARGIN;
  #pragma unroll
  for(int j=0;j<8;j++){
    if(orig[j] >= 0 && sv[j] > thr){
      int slot = atomicAdd(&sel_count[b], 1);
      if(slot < CAP) sel_list[b*CAP + slot] = orig[j];
    }
  }
}

// ---------------- phase-2: exact 3-pass rescoring of selected rows ------------
__global__ __launch_bounds__(256)
void k_phase2(const float* __restrict__ xs,
              const char* __restrict__ imgf,
              const float* __restrict__ avec,
              const float* __restrict__ energy,
              const int* __restrict__ sel_count,
              const int* __restrict__ sel_list,
              float* __restrict__ p2buf){
  __shared__ us16 A2[32][80];     // hi bytes [0,64), lo at +80, row stride 160B
  __shared__ float s2[4][32];
  const int b = blockIdx.x >> 4, cb = blockIdx.x & 15;
  const int t = threadIdx.x, w = t >> 6, lane = t & 63;
  const int lm = lane & 15, lk = lane >> 4;
  const int ct = cb*4 + w;                    // ct16 index 0..63
  const int col = ct*16 + lm;
  const float av  = avec[b*DIM + col];
  const float evv = energy[col];
  char* lds = (char*)&A2[0][0];
  const int count = min(sel_count[b], CAP);
  const int ri = t >> 3, seg = t & 7;
  // 2-bit XOR key: must stay inside the 64-byte hi field (R6 lesson)
  const int wbyte = ri*160 + ((seg*8) ^ ((ri&3)<<4));
  const char* a_rd = lds + lm*160 + ((lk*16) ^ ((lm&3)<<4));

  for(int c0 = 0; c0 < count; c0 += 32){
    const int li = c0 + ri;
    const int row = sel_list[b*CAP + min(li, count-1)];
    const float* rp = xs + ((size_t)b*NS + row)*DIM + seg*4;
    f32x4 acc[2];
    acc[0] = (f32x4){0.f,0.f,0.f,0.f};
    acc[1] = (f32x4){0.f,0.f,0.f,0.f};
    for(int kt=0; kt<32; kt++){
      __syncthreads();                        // prior kt's frag reads consumed
      float4 v = *(const float4*)(rp + kt*32);
      float fv[4] = {v.x, v.y, v.z, v.w};
      us16x4 hi, lo;
      #pragma unroll
      for(int e=0;e<4;e++){
        short a, l; split_bf16(fv[e], a, l);
        hi[e] = (us16)a; lo[e] = (us16)l;
      }
      *(us16x4*)(lds + wbyte)      = hi;
      *(us16x4*)(lds + wbyte + 80) = lo;
      __syncthreads();
      const char* fbb = imgf + ((size_t)(kt*64 + ct)*2)*1024 + lane*16;
      short8 bh = *(const short8*)(fbb);
      short8 bl = *(const short8*)(fbb + 1024);
      short8 fah[2], fal[2];
      #pragma unroll
      for(int m=0;m<2;m++){
        fah[m] = *(const short8*)(a_rd + m*2560);
        fal[m] = *(const short8*)(a_rd + m*2560 + 80);
      }
      #pragma unroll
      for(int m=0;m<2;m++)
        acc[m] = __builtin_amdgcn_mfma_f32_16x16x32_bf16(fah[m], bh, acc[m], 0,0,0);
      #pragma unroll
      for(int m=0;m<2;m++)
        acc[m] = __builtin_amdgcn_mfma_f32_16x16x32_bf16(fah[m], bl, acc[m], 0,0,0);
      #pragma unroll
      for(int m=0;m<2;m++)
        acc[m] = __builtin_amdgcn_mfma_f32_16x16x32_bf16(fal[m], bh, acc[m], 0,0,0);
    }
    float s[2][4];
    #pragma unroll
    for(int m=0;m<2;m++)
      #pragma unroll
      for(int j=0;j<4;j++){
        float v = evv * fast_tanh(av + acc[m][j]);
        v += __shfl_xor(v,1); v += __shfl_xor(v,2);
        v += __shfl_xor(v,4); v += __shfl_xor(v,8);
        s[m][j] = v;
      }
    __syncthreads();
    if(lm == 0){
      #pragma unroll
      for(int m=0;m<2;m++)
        #pragma unroll
        for(int j=0;j<4;j++) s2[w][m*16 + lk*4 + j] = s[m][j];
    }
    __syncthreads();
    if(t < 32){
      float sum = s2[0][t] + s2[1][t] + s2[2][t] + s2[3][t];
      p2buf[((size_t)b*16 + cb)*CAP + c0 + t] = sum;
    }
  }
}

// ---------------- masked softmax with fused exact-score scatter ---------------
__global__ void k_softmax(const float* __restrict__ scores,
                          const float* __restrict__ p2buf,
                          const int* __restrict__ sel_count,
                          const int* __restrict__ sel_list,
                          const int* __restrict__ mask,
                          float* __restrict__ attn){
  const int b = blockIdx.x, t = threadIdx.x;
  const int w = t >> 6, lane = t & 63;
  __shared__ float sc[NS];      // 8KB: corrected scores
  __shared__ float red[4];
  #pragma unroll
  for(int j=0;j<8;j++) sc[j*256+t] = scores[b*NS + j*256 + t];
  __syncthreads();
  const int count = min(sel_count[b], CAP);
  for(int s0 = t; s0 < count; s0 += 256){
    float s = 0.f;
    #pragma unroll
    for(int c=0;c<16;c++) s += p2buf[((size_t)b*16 + c)*CAP + s0];
    sc[sel_list[b*CAP + s0]] = s;
  }
  __syncthreads();
  float sv[8]; int mv[8];
  float m = -3.4e38f;
  #pragma unroll
  for(int j=0;j<8;j++){
    const int i = j*256 + t;
    sv[j] = sc[i];
    mv[j] = mask[b*NS + i];
    if(mv[j] && sv[j] > m) m = sv[j];
  }
  #pragma unroll
  for(int off=1; off<64; off<<=1) m = fmaxf(m, __shfl_xor(m, off));
  if(lane==0) red[w] = m;
  __syncthreads();
  m = fmaxf(fmaxf(red[0],red[1]), fmaxf(red[2],red[3]));
  __syncthreads();
  float ev[8]; float l = 0.f;
  #pragma unroll
  for(int j=0;j<8;j++){
    ev[j] = mv[j] ? __builtin_exp2f((sv[j]-m)*1.4426950408889634f) : 0.f;
    l += ev[j];
  }
  #pragma unroll
  for(int off=1; off<64; off<<=1) l += __shfl_xor(l, off);
  if(lane==0) red[w] = l;
  __syncthreads();
  l = red[0]+red[1]+red[2]+red[3];
  const float inv = 1.0f/l;
  #pragma unroll
  for(int j=0;j<8;j++) attn[b*NS + j*256 + t] = ev[j]*inv;
}

// ---------------- ctx = attn @ xs, chunked (256 blocks) ----------------
__global__ void k_ctx_partial(const float* __restrict__ attn,
                              const float* __restrict__ xs,
                              float* __restrict__ cp){
  const int b = blockIdx.x >> 3, ch = blockIdx.x & 7;
  const int t = threadIdx.x;
  __shared__ float al[256];
  al[t] = attn[b*NS + ch*256 + t];
  __syncthreads();
  float4 acc = {0.f,0.f,0.f,0.f};
  const float* base = xs + (size_t)(b*NS + ch*256)*DIM + t*4;
  for(int i=0;i<256;i++){
    float wv = al[i];                 // uniform across block
    if(wv > 1e-12f){                  // contribution < 1e-8, deterministic
      float4 x = *(const float4*)(base + (size_t)i*DIM);
      acc.x += wv*x.x; acc.y += wv*x.y; acc.z += wv*x.z; acc.w += wv*x.w;
    }
  }
  *(float4*)(cp + ((size_t)ch*NB + b)*DIM + t*4) = acc;
}

__global__ void k_ctx_reduce(const float* __restrict__ cp, float* __restrict__ ctx){
  int i = blockIdx.x*256 + threadIdx.x;
  float s = 0.f;
  #pragma unroll
  for(int ch=0; ch<8; ch++) s += cp[(size_t)ch*NB*DIM + i];
  ctx[i] = s;
}

extern "C" void kernel_launch(void* const* d_in, const int* in_sizes, int n_in,
                              void* d_out, int out_size, void* d_ws, size_t ws_size,
                              hipStream_t stream) {
  const float* kin    = (const float*)d_in[0];   // [32,1024]
  const float* xs     = (const float*)d_in[1];   // [32,2048,1024]
  const int*   mask   = (const int*)d_in[2];     // [32,2048]
  const float* wa     = (const float*)d_in[3];   // [1024,1024]
  const float* wb     = (const float*)d_in[4];   // [1024,1024]
  const float* energy = (const float*)d_in[5];   // [1024]
  float* out  = (float*)d_out;
  float* ctx  = out;            // [32,1024]
  float* attn = out + NB*DIM;   // [32,2048]

  char* ws = (char*)d_ws;
  float* partial   = (float*)(ws);                       // 2 MB    @ 0
  float* avec      = (float*)(ws + 2097152);             // 128 KB
  float* scores    = (float*)(ws + 2228224);             // 256 KB
  float* cp        = (float*)(ws + 2490368);             // 1 MB
  char*  imgf      = ws + 3538944;                       // 4 MB (frag hi/lo)
  char*  img1      = ws + 7733248;                       // 2 MB (gload hi, BK=32)
  int*   sel_count = (int*)(ws + 9830400);               // 128 B
  int*   sel_list  = (int*)(ws + 9830528);               // 32 KB
  float* p2buf     = (float*)(ws + 9863296);             // 512 KB
  int*   cidx      = (int*)(ws + 10387584);              // 256 KB
  int*   cnt       = (int*)(ws + 10649728);              // 128 B

  k_prep       <<<1696, 256, 0, stream>>>(wb, kin, wa, mask, imgf, img1, avec,
                                          cidx, cnt, sel_count);
  k_gemm_approx<<<2048, 256, 0, stream>>>(xs, img1, avec, energy, cidx, cnt, partial);
  k_select     <<<NB, 256, 0, stream>>>(partial, cidx, cnt, scores, sel_count, sel_list);
  k_phase2     <<<512, 256, 0, stream>>>(xs, imgf, avec, energy, sel_count, sel_list, p2buf);
  k_softmax    <<<NB, 256, 0, stream>>>(scores, p2buf, sel_count, sel_list, mask, attn);
  k_ctx_partial<<<256, 256, 0, stream>>>(attn, xs, cp);
  k_ctx_reduce <<<128, 256, 0, stream>>>(cp, ctx);
}

// Round 12
// 276.715 us; speedup vs baseline: 3.8317x; 1.0955x over previous
//
#include <hip/hip_runtime.h>
#include <hip/hip_bf16.h>

#define NB 32
#define NS 2048
#define DIM 1024
#define NM (NB*NS)   // 65536 rows
#define CAP 256      // max rescored rows per batch
#define SEL_MARGIN 24.0f

typedef __attribute__((ext_vector_type(8))) short short8;
typedef __attribute__((ext_vector_type(4))) float f32x4;
typedef __attribute__((ext_vector_type(4))) unsigned short us16x4;
typedef unsigned short us16;
typedef unsigned int   u32;
typedef __attribute__((address_space(3))) void lds_void;
typedef __attribute__((address_space(1))) void glb_void;

__device__ __forceinline__ void gload16(const void* g, void* l){
  __builtin_amdgcn_global_load_lds((const glb_void*)g, (lds_void*)l, 16, 0, 0);
}

__device__ __forceinline__ float fast_tanh(float x){
  float e = __builtin_exp2f(x * 2.8853900817779268f); // e^{2x}
  return 1.0f - 2.0f/(e + 1.0f);
}

__device__ __forceinline__ void split_bf16(float x, short &hi, short &lo){
  u32 u = __float_as_uint(x);
  float hf = __uint_as_float(u & 0xFFFF0000u);
  hi = (short)(u >> 16);
  lo = (short)(__float_as_uint(x - hf) >> 16);
}

// ---------------- fused prep: wb images + avec + mask compaction --------------
// blocks 0..1023: phase-2 B image (frag-ordered hi/lo)        [verified R5-R11]
// blocks 1024..1535: phase-1 B image (pre-swizzled gload hi)  [verified R7-R11]
// blocks 1536..1663: avec = k @ Wa^T (exact f32)
// blocks 1664..1695: per-batch stable compaction of unmasked rows
__global__ void k_prep(const float* __restrict__ wb,
                       const float* __restrict__ kin,
                       const float* __restrict__ wa,
                       const int* __restrict__ mask,
                       char* __restrict__ imgf,
                       char* __restrict__ img1,
                       float* __restrict__ avec,
                       int* __restrict__ cidx,
                       int* __restrict__ cnt,
                       int* __restrict__ sel_count){
  __shared__ float4 kl[256];
  __shared__ int tc[256];
  __shared__ int tot;
  const int h = blockIdx.x, t = threadIdx.x;
  if(h == 0 && t < NB) sel_count[t] = 0;
  if(h < 1024){
    // 16B slot = ((kt*64 + ct16)*2 + hl)*64 + lane ; Wb[ct16*16+(lane&15)]
    const int tid = h*256 + t;
    const int kt   = tid >> 13;
    const int ct16 = (tid >> 7) & 63;
    const int hl   = (tid >> 6) & 1;
    const int lane = tid & 63;
    const int col  = ct16*16 + (lane & 15);
    const int k0   = kt*32 + (lane >> 4)*8;
    const float* src = wb + (size_t)col*DIM + k0;
    float4 v0 = *(const float4*)src;
    float4 v1 = *(const float4*)(src + 4);
    float fv[8] = {v0.x,v0.y,v0.z,v0.w,v1.x,v1.y,v1.z,v1.w};
    short8 out;
    #pragma unroll
    for(int j=0;j<8;j++){
      short hi,lo; split_bf16(fv[j],hi,lo);
      out[j] = hl ? lo : hi;
    }
    *(short8*)(imgf + (size_t)tid*16) = out;
  } else if(h < 1536){
    // [kt(32)][cb(4)][16KB]; byte B: row=B>>7, inner=B&127,
    // ix = inner ^ ((row&7)<<4): col = cb*256 + (ix>>6)*128 + row,
    // k = kt*32 + ((ix>>4)&3)*8 + (B&15)/2 (hi bf16)
    const int tid = (h-1024)*256 + t;
    const int tile = tid >> 10;
    const int kt = tile >> 2, cb = tile & 3;
    const int byt = (tid & 1023) * 16;
    const int row = byt >> 7, inner = byt & 127;
    const int ix = inner ^ ((row & 7) << 4);
    const int colhi = ix >> 6, lkk = (ix >> 4) & 3;
    const int col = cb*256 + colhi*128 + row;
    const float* src = wb + (size_t)col*DIM + kt*32 + lkk*8;
    float4 v0 = *(const float4*)src;
    float4 v1 = *(const float4*)(src + 4);
    float fv[8] = {v0.x,v0.y,v0.z,v0.w,v1.x,v1.y,v1.z,v1.w};
    short8 out;
    #pragma unroll
    for(int j=0;j<8;j++) out[j] = (short)(__float_as_uint(fv[j]) >> 16);
    *(short8*)(img1 + (size_t)tid*16) = out;
  } else if(h < 1664){
    const int hb = h - 1536;
    const int b = hb >> 2, oc = hb & 3;
    kl[t] = *(const float4*)(kin + b*DIM + t*4);
    __syncthreads();
    const int o = oc*256 + t;
    const float4* wrow = (const float4*)(wa + (size_t)o*DIM);
    float acc = 0.f;
    for(int i=0;i<256;i++){
      float4 wv = wrow[i]; float4 kk = kl[i];
      acc += wv.x*kk.x + wv.y*kk.y + wv.z*kk.z + wv.w*kk.w;
    }
    avec[b*DIM + o] = acc;
  } else {
    // ---- stable compaction of unmasked rows for batch b ----
    const int b = h - 1664;
    int mv[8]; int c = 0;
    #pragma unroll
    for(int e=0;e<8;e++){ mv[e] = mask[b*NS + t*8 + e]; c += (mv[e] ? 1 : 0); }
    tc[t] = c;
    __syncthreads();
    for(int d=1; d<256; d<<=1){          // Hillis-Steele inclusive scan
      int v = tc[t];
      int add = (t >= d) ? tc[t-d] : 0;
      __syncthreads();
      tc[t] = v + add;
      __syncthreads();
    }
    const int excl = tc[t] - c;
    if(t == 255) tot = tc[t];
    __syncthreads();
    int pos = excl;
    #pragma unroll
    for(int e=0;e<8;e++){
      if(mv[e]) cidx[b*NS + (pos++)] = t*8 + e;
    }
    const int total = tot;
    if(t == 0) cnt[b] = total;
    for(int p = total + t; p < NS; p += 256) cidx[b*NS + p] = 0;  // safe pad
  }
}

// ---------------- phase-1: 1-pass truncated-bf16 GEMM over COMPACTED rows -----
// R9/R11-verified structure. R12 delta: DENSE work remap — blocks 0..1151 cover
// tiles 0..8 of every batch (XCD-chunked, 4 cb-blocks of one A-panel adjacent);
// blocks 1152.. cover tiles 9..15 (active only if cnt>1152 — correctness net).
__global__ __launch_bounds__(256,2)
void k_gemm_approx(const float* __restrict__ xs,
                   const char* __restrict__ img1,
                   const float* __restrict__ avec,
                   const float* __restrict__ energy,
                   const int* __restrict__ cidx,
                   const int* __restrict__ cnt,
                   float* __restrict__ partial){
  __shared__ us16 Abuf[128][40];      // hi only; row stride 80B
  __shared__ us16 Bbuf[2][128][64];   // 2 x 16KB, filled by global_load_lds

  const int h = blockIdx.x;                   // 2048 blocks
  int bidx, tile, cb;
  if(h < 1152){                               // dense region: 32 b x 9 t x 4 cb
    const int xcd = h / 144, idx = h % 144;   // 8 XCD chunks of 36 pairs
    const int pair = xcd*36 + (idx >> 2);     // 0..287 = batch*9 + tile
    bidx = pair / 9; tile = pair % 9; cb = idx & 3;
  } else {                                    // rare region: tiles 9..15
    const int h2 = h - 1152;
    bidx = h2 / 28; tile = 9 + ((h2 % 28) >> 2); cb = h2 & 3;
  }
  if(tile*128 >= cnt[bidx]) return;           // tile beyond unmasked count
  const int t  = threadIdx.x;
  const int w  = t >> 6, lane = t & 63;
  const int wr = w >> 1, wc = w & 1;          // wave tile: 64 rows x 128 cols
  const int lm = lane & 15, lk = lane >> 4;
  const int sr = t >> 1, sh = t & 1;

  const int orig = cidx[bidx*NS + tile*128 + sr];   // gathered source row
  const float* ap = xs + ((size_t)bidx*NS + orig)*DIM + sh*16;
  const char*  bsrc = img1;                   // + (kt*4+cb)*16384

  const char* a_rd = (const char*)&Abuf[0][0] + (wr*64 + lm)*80 + ((lk*16) ^ ((lm&3)<<4));
  const int boff = (wc*64 + lk*16) ^ ((lm&7)<<4);

  f32x4 acc[4][8];
  #pragma unroll
  for(int m=0;m<4;m++)
    #pragma unroll
    for(int n=0;n<8;n++) acc[m][n] = (f32x4){0.f,0.f,0.f,0.f};

  // prologue: A(0) regs FIRST (oldest in FIFO), then B(0) gloads
  float4 ar0 = *(const float4*)(ap+0),  ar1 = *(const float4*)(ap+4);
  float4 ar2 = *(const float4*)(ap+8),  ar3 = *(const float4*)(ap+12);
  {
    const char* gs = bsrc + (size_t)cb*16384 + t*16;
    char* ld = (char*)&Bbuf[0][0][0] + t*16;
    #pragma unroll
    for(int c=0;c<4;c++) gload16(gs + c*4096, ld + c*4096);
  }

  for(int kt=0; kt<32; kt++){
    const int cur = kt & 1;
    // bar1: all waves' frag reads of tile kt-1 done (lgkm only — NO vmem drain)
    asm volatile("s_waitcnt lgkmcnt(0)" ::: "memory");
    __builtin_amdgcn_sched_barrier(0);
    __builtin_amdgcn_s_barrier();
    {   // truncate-store A(kt) from ar
      float fv[16];
      *(float4*)(fv+0)=ar0; *(float4*)(fv+4)=ar1;
      *(float4*)(fv+8)=ar2; *(float4*)(fv+12)=ar3;
      short8 h0, h1;
      #pragma unroll
      for(int j=0;j<8;j++){ h0[j] = (short)(__float_as_uint(fv[j])>>16);
                            h1[j] = (short)(__float_as_uint(fv[8+j])>>16); }
      char* abase = (char*)&Abuf[0][0] + sr*80;
      const int swz = (sr & 3) << 4;
      *(short8*)(abase + ((sh*32     ) ^ swz)) = h0;
      *(short8*)(abase + ((sh*32 + 16) ^ swz)) = h1;
    }
    if(kt < 31){
      const float* a2 = ap + (kt+1)*32;   // A(kt+1) regs first (oldest)
      ar0 = *(const float4*)(a2+0);  ar1 = *(const float4*)(a2+4);
      ar2 = *(const float4*)(a2+8);  ar3 = *(const float4*)(a2+12);
      {                                   // then B(kt+1) gloads
        const char* gs = bsrc + (size_t)((kt+1)*4 + cb)*16384 + t*16;
        char* ld = (char*)&Bbuf[cur^1][0][0] + t*16;
        #pragma unroll
        for(int c=0;c<4;c++) gload16(gs + c*4096, ld + c*4096);
      }
      // FIFO: [B(kt)4, A(kt+1)4, B(kt+1)4] -> vmcnt(8): B(kt) landed,
      // next-tile loads stay in flight. lgkm(0) = A ds_writes visible.
      asm volatile("s_waitcnt vmcnt(8) lgkmcnt(0)" ::: "memory");
    } else {
      asm volatile("s_waitcnt vmcnt(0) lgkmcnt(0)" ::: "memory");
    }
    __builtin_amdgcn_sched_barrier(0);
    __builtin_amdgcn_s_barrier();       // bar2: tile kt fully in LDS

    short8 fa[4], fb[8];
    const char* bb = (const char*)&Bbuf[cur][0][0] + lm*128 + boff;
    #pragma unroll
    for(int m=0;m<4;m++) fa[m] = *(const short8*)(a_rd + m*1280);
    #pragma unroll
    for(int n=0;n<8;n++) fb[n] = *(const short8*)(bb + n*2048);
    #pragma unroll
    for(int m=0;m<4;m++)
      #pragma unroll
      for(int n=0;n<8;n++)
        acc[m][n] = __builtin_amdgcn_mfma_f32_16x16x32_bf16(fa[m], fb[n], acc[m][n], 0,0,0);
  }

  // epilogue: partial[cb*2+wc][compacted row] over wave's 128 cols
  float av[8], ev[8];
  #pragma unroll
  for(int n=0;n<8;n++){
    const int col = cb*256 + wc*128 + n*16 + lm;
    av[n] = avec[bidx*DIM + col];
    ev[n] = energy[col];
  }
  #pragma unroll
  for(int m=0;m<4;m++){
    float rs[4];
    #pragma unroll
    for(int j=0;j<4;j++){
      float s = 0.f;
      #pragma unroll
      for(int n=0;n<8;n++) s += ev[n]*fast_tanh(av[n] + acc[m][n][j]);
      s += __shfl_xor(s,1); s += __shfl_xor(s,2);
      s += __shfl_xor(s,4); s += __shfl_xor(s,8);
      rs[j] = s;
    }
    if(lm == 0){
      float4 st = {rs[0], rs[1], rs[2], rs[3]};
      *(float4*)(partial + (size_t)(cb*2+wc)*NM + bidx*NS + tile*128 + wr*64 + m*16 + lk*4) = st;
    }
  }
}

// ---------------- select over compacted rows; scatter scores to orig ids ------
__global__ void k_select(const float* __restrict__ partial,
                         const int* __restrict__ cidx,
                         const int* __restrict__ cnt,
                         float* __restrict__ scores,
                         int* __restrict__ sel_count,
                         int* __restrict__ sel_list){
  const int b = blockIdx.x, t = threadIdx.x;
  const int w = t >> 6, lane = t & 63;
  __shared__ float red[4];
  const int cnt_b = cnt[b];
  float sv[8]; int orig[8];
  float m = -3.4e38f;
  #pragma unroll
  for(int j=0;j<8;j++){
    const int i = j*256 + t;                  // compacted index
    if(i < cnt_b){
      float s = 0.f;
      #pragma unroll
      for(int c=0;c<8;c++) s += partial[(size_t)c*NM + b*NS + i];
      sv[j] = s;
      orig[j] = cidx[b*NS + i];
      scores[b*NS + orig[j]] = s;             // all compacted rows are unmasked
      if(s > m) m = s;
    } else { sv[j] = -3.4e38f; orig[j] = -1; }
  }
  #pragma unroll
  for(int off=1; off<64; off<<=1) m = fmaxf(m, __shfl_xor(m, off));
  if(lane==0) red[w] = m;
  __syncthreads();
  m = fmaxf(fmaxf(red[0],red[1]), fmaxf(red[2],red[3]));
  const float thr = m - SEL_MARGIN;
  #pragma unroll
  for(int j=0;j<8;j++){
    if(orig[j] >= 0 && sv[j] > thr){
      int slot = atomicAdd(&sel_count[b], 1);
      if(slot < CAP) sel_list[b*CAP + slot] = orig[j];
    }
  }
}

// ---------------- phase-2: exact 3-pass rescoring of selected rows ------------
__global__ __launch_bounds__(256)
void k_phase2(const float* __restrict__ xs,
              const char* __restrict__ imgf,
              const float* __restrict__ avec,
              const float* __restrict__ energy,
              const int* __restrict__ sel_count,
              const int* __restrict__ sel_list,
              float* __restrict__ p2buf){
  __shared__ us16 A2[32][80];     // hi bytes [0,64), lo at +80, row stride 160B
  __shared__ float s2[4][32];
  const int b = blockIdx.x >> 4, cb = blockIdx.x & 15;
  const int t = threadIdx.x, w = t >> 6, lane = t & 63;
  const int lm = lane & 15, lk = lane >> 4;
  const int ct = cb*4 + w;                    // ct16 index 0..63
  const int col = ct*16 + lm;
  const float av  = avec[b*DIM + col];
  const float evv = energy[col];
  char* lds = (char*)&A2[0][0];
  const int count = min(sel_count[b], CAP);
  const int ri = t >> 3, seg = t & 7;
  // 2-bit XOR key: must stay inside the 64-byte hi field (R6 lesson)
  const int wbyte = ri*160 + ((seg*8) ^ ((ri&3)<<4));
  const char* a_rd = lds + lm*160 + ((lk*16) ^ ((lm&3)<<4));

  for(int c0 = 0; c0 < count; c0 += 32){
    const int li = c0 + ri;
    const int row = sel_list[b*CAP + min(li, count-1)];
    const float* rp = xs + ((size_t)b*NS + row)*DIM + seg*4;
    f32x4 acc[2];
    acc[0] = (f32x4){0.f,0.f,0.f,0.f};
    acc[1] = (f32x4){0.f,0.f,0.f,0.f};
    for(int kt=0; kt<32; kt++){
      __syncthreads();                        // prior kt's frag reads consumed
      float4 v = *(const float4*)(rp + kt*32);
      float fv[4] = {v.x, v.y, v.z, v.w};
      us16x4 hi, lo;
      #pragma unroll
      for(int e=0;e<4;e++){
        short a, l; split_bf16(fv[e], a, l);
        hi[e] = (us16)a; lo[e] = (us16)l;
      }
      *(us16x4*)(lds + wbyte)      = hi;
      *(us16x4*)(lds + wbyte + 80) = lo;
      __syncthreads();
      const char* fbb = imgf + ((size_t)(kt*64 + ct)*2)*1024 + lane*16;
      short8 bh = *(const short8*)(fbb);
      short8 bl = *(const short8*)(fbb + 1024);
      short8 fah[2], fal[2];
      #pragma unroll
      for(int m=0;m<2;m++){
        fah[m] = *(const short8*)(a_rd + m*2560);
        fal[m] = *(const short8*)(a_rd + m*2560 + 80);
      }
      #pragma unroll
      for(int m=0;m<2;m++)
        acc[m] = __builtin_amdgcn_mfma_f32_16x16x32_bf16(fah[m], bh, acc[m], 0,0,0);
      #pragma unroll
      for(int m=0;m<2;m++)
        acc[m] = __builtin_amdgcn_mfma_f32_16x16x32_bf16(fah[m], bl, acc[m], 0,0,0);
      #pragma unroll
      for(int m=0;m<2;m++)
        acc[m] = __builtin_amdgcn_mfma_f32_16x16x32_bf16(fal[m], bh, acc[m], 0,0,0);
    }
    float s[2][4];
    #pragma unroll
    for(int m=0;m<2;m++)
      #pragma unroll
      for(int j=0;j<4;j++){
        float v = evv * fast_tanh(av + acc[m][j]);
        v += __shfl_xor(v,1); v += __shfl_xor(v,2);
        v += __shfl_xor(v,4); v += __shfl_xor(v,8);
        s[m][j] = v;
      }
    __syncthreads();
    if(lm == 0){
      #pragma unroll
      for(int m=0;m<2;m++)
        #pragma unroll
        for(int j=0;j<4;j++) s2[w][m*16 + lk*4 + j] = s[m][j];
    }
    __syncthreads();
    if(t < 32){
      float sum = s2[0][t] + s2[1][t] + s2[2][t] + s2[3][t];
      p2buf[((size_t)b*16 + cb)*CAP + c0 + t] = sum;
    }
  }
}

// ---------------- masked softmax with fused exact-score scatter ---------------
__global__ void k_softmax(const float* __restrict__ scores,
                          const float* __restrict__ p2buf,
                          const int* __restrict__ sel_count,
                          const int* __restrict__ sel_list,
                          const int* __restrict__ mask,
                          float* __restrict__ attn){
  const int b = blockIdx.x, t = threadIdx.x;
  const int w = t >> 6, lane = t & 63;
  __shared__ float sc[NS];      // 8KB: corrected scores
  __shared__ float red[4];
  #pragma unroll
  for(int j=0;j<8;j++) sc[j*256+t] = scores[b*NS + j*256 + t];
  __syncthreads();
  const int count = min(sel_count[b], CAP);
  for(int s0 = t; s0 < count; s0 += 256){
    float s = 0.f;
    #pragma unroll
    for(int c=0;c<16;c++) s += p2buf[((size_t)b*16 + c)*CAP + s0];
    sc[sel_list[b*CAP + s0]] = s;
  }
  __syncthreads();
  float sv[8]; int mv[8];
  float m = -3.4e38f;
  #pragma unroll
  for(int j=0;j<8;j++){
    const int i = j*256 + t;
    sv[j] = sc[i];
    mv[j] = mask[b*NS + i];
    if(mv[j] && sv[j] > m) m = sv[j];
  }
  #pragma unroll
  for(int off=1; off<64; off<<=1) m = fmaxf(m, __shfl_xor(m, off));
  if(lane==0) red[w] = m;
  __syncthreads();
  m = fmaxf(fmaxf(red[0],red[1]), fmaxf(red[2],red[3]));
  __syncthreads();
  float ev[8]; float l = 0.f;
  #pragma unroll
  for(int j=0;j<8;j++){
    ev[j] = mv[j] ? __builtin_exp2f((sv[j]-m)*1.4426950408889634f) : 0.f;
    l += ev[j];
  }
  #pragma unroll
  for(int off=1; off<64; off<<=1) l += __shfl_xor(l, off);
  if(lane==0) red[w] = l;
  __syncthreads();
  l = red[0]+red[1]+red[2]+red[3];
  const float inv = 1.0f/l;
  #pragma unroll
  for(int j=0;j<8;j++) attn[b*NS + j*256 + t] = ev[j]*inv;
}

// ---------------- ctx = attn @ xs, chunked (256 blocks) ----------------
__global__ void k_ctx_partial(const float* __restrict__ attn,
                              const float* __restrict__ xs,
                              float* __restrict__ cp){
  const int b = blockIdx.x >> 3, ch = blockIdx.x & 7;
  const int t = threadIdx.x;
  __shared__ float al[256];
  al[t] = attn[b*NS + ch*256 + t];
  __syncthreads();
  float4 acc = {0.f,0.f,0.f,0.f};
  const float* base = xs + (size_t)(b*NS + ch*256)*DIM + t*4;
  for(int i=0;i<256;i++){
    float wv = al[i];                 // uniform across block
    if(wv > 1e-12f){                  // contribution < 1e-8, deterministic
      float4 x = *(const float4*)(base + (size_t)i*DIM);
      acc.x += wv*x.x; acc.y += wv*x.y; acc.z += wv*x.z; acc.w += wv*x.w;
    }
  }
  *(float4*)(cp + ((size_t)ch*NB + b)*DIM + t*4) = acc;
}

__global__ void k_ctx_reduce(const float* __restrict__ cp, float* __restrict__ ctx){
  int i = blockIdx.x*256 + threadIdx.x;
  float s = 0.f;
  #pragma unroll
  for(int ch=0; ch<8; ch++) s += cp[(size_t)ch*NB*DIM + i];
  ctx[i] = s;
}

extern "C" void kernel_launch(void* const* d_in, const int* in_sizes, int n_in,
                              void* d_out, int out_size, void* d_ws, size_t ws_size,
                              hipStream_t stream) {
  const float* kin    = (const float*)d_in[0];   // [32,1024]
  const float* xs     = (const float*)d_in[1];   // [32,2048,1024]
  const int*   mask   = (const int*)d_in[2];     // [32,2048]
  const float* wa     = (const float*)d_in[3];   // [1024,1024]
  const float* wb     = (const float*)d_in[4];   // [1024,1024]
  const float* energy = (const float*)d_in[5];   // [1024]
  float* out  = (float*)d_out;
  float* ctx  = out;            // [32,1024]
  float* attn = out + NB*DIM;   // [32,2048]

  char* ws = (char*)d_ws;
  float* partial   = (float*)(ws);                       // 2 MB    @ 0
  float* avec      = (float*)(ws + 2097152);             // 128 KB
  float* scores    = (float*)(ws + 2228224);             // 256 KB
  float* cp        = (float*)(ws + 2490368);             // 1 MB
  char*  imgf      = ws + 3538944;                       // 4 MB (frag hi/lo)
  char*  img1      = ws + 7733248;                       // 2 MB (gload hi, BK=32)
  int*   sel_count = (int*)(ws + 9830400);               // 128 B
  int*   sel_list  = (int*)(ws + 9830528);               // 32 KB
  float* p2buf     = (float*)(ws + 9863296);             // 512 KB
  int*   cidx      = (int*)(ws + 10387584);              // 256 KB
  int*   cnt       = (int*)(ws + 10649728);              // 128 B

  k_prep       <<<1696, 256, 0, stream>>>(wb, kin, wa, mask, imgf, img1, avec,
                                          cidx, cnt, sel_count);
  k_gemm_approx<<<2048, 256, 0, stream>>>(xs, img1, avec, energy, cidx, cnt, partial);
  k_select     <<<NB, 256, 0, stream>>>(partial, cidx, cnt, scores, sel_count, sel_list);
  k_phase2     <<<512, 256, 0, stream>>>(xs, imgf, avec, energy, sel_count, sel_list, p2buf);
  k_softmax    <<<NB, 256, 0, stream>>>(scores, p2buf, sel_count, sel_list, mask, attn);
  k_ctx_partial<<<256, 256, 0, stream>>>(attn, xs, cp);
  k_ctx_reduce <<<128, 256, 0, stream>>>(cp, ctx);
}

// Round 13
// 254.834 us; speedup vs baseline: 4.1607x; 1.0859x over previous
//
#include <hip/hip_runtime.h>
#include <hip/hip_bf16.h>

#define NB 32
#define NS 2048
#define DIM 1024
#define NM (NB*NS)   // 65536 rows
#define CAP 256      // max rescored rows per batch
#define SEL_MARGIN 24.0f

typedef __attribute__((ext_vector_type(8))) short short8;
typedef __attribute__((ext_vector_type(4))) float f32x4;
typedef __attribute__((ext_vector_type(4))) unsigned short us16x4;
typedef unsigned short us16;
typedef unsigned int   u32;
typedef __attribute__((address_space(3))) void lds_void;
typedef __attribute__((address_space(1))) void glb_void;

__device__ __forceinline__ void gload16(const void* g, void* l){
  __builtin_amdgcn_global_load_lds((const glb_void*)g, (lds_void*)l, 16, 0, 0);
}

__device__ __forceinline__ float fast_tanh(float x){
  float e = __builtin_exp2f(x * 2.8853900817779268f); // e^{2x}
  return 1.0f - 2.0f/(e + 1.0f);
}

__device__ __forceinline__ void split_bf16(float x, short &hi, short &lo){
  u32 u = __float_as_uint(x);
  float hf = __uint_as_float(u & 0xFFFF0000u);
  hi = (short)(u >> 16);
  lo = (short)(__float_as_uint(x - hf) >> 16);
}

// ---------------- fused prep: wb images + avec + mask compaction --------------
__global__ void k_prep(const float* __restrict__ wb,
                       const float* __restrict__ kin,
                       const float* __restrict__ wa,
                       const int* __restrict__ mask,
                       char* __restrict__ imgf,
                       char* __restrict__ img1,
                       float* __restrict__ avec,
                       int* __restrict__ cidx,
                       int* __restrict__ cnt,
                       int* __restrict__ sel_count){
  __shared__ float4 kl[256];
  __shared__ int tc[256];
  __shared__ int tot;
  const int h = blockIdx.x, t = threadIdx.x;
  if(h == 0 && t < NB) sel_count[t] = 0;
  if(h < 1024){
    // phase-2 B image: 16B slot = ((kt*64 + ct16)*2 + hl)*64 + lane
    const int tid = h*256 + t;
    const int kt   = tid >> 13;
    const int ct16 = (tid >> 7) & 63;
    const int hl   = (tid >> 6) & 1;
    const int lane = tid & 63;
    const int col  = ct16*16 + (lane & 15);
    const int k0   = kt*32 + (lane >> 4)*8;
    const float* src = wb + (size_t)col*DIM + k0;
    float4 v0 = *(const float4*)src;
    float4 v1 = *(const float4*)(src + 4);
    float fv[8] = {v0.x,v0.y,v0.z,v0.w,v1.x,v1.y,v1.z,v1.w};
    short8 out;
    #pragma unroll
    for(int j=0;j<8;j++){
      short hi,lo; split_bf16(fv[j],hi,lo);
      out[j] = hl ? lo : hi;
    }
    *(short8*)(imgf + (size_t)tid*16) = out;
  } else if(h < 1536){
    // phase-1 B image = [kt(32)][cb(4)][16KB]; byte B: row=B>>7, inner=B&127,
    // ix = inner ^ ((row&7)<<4): col = cb*256 + (ix>>6)*128 + row,
    // k = kt*32 + ((ix>>4)&3)*8 + (B&15)/2 (hi bf16)
    const int tid = (h-1024)*256 + t;
    const int tile = tid >> 10;
    const int kt = tile >> 2, cb = tile & 3;
    const int byt = (tid & 1023) * 16;
    const int row = byt >> 7, inner = byt & 127;
    const int ix = inner ^ ((row & 7) << 4);
    const int colhi = ix >> 6, lkk = (ix >> 4) & 3;
    const int col = cb*256 + colhi*128 + row;
    const float* src = wb + (size_t)col*DIM + kt*32 + lkk*8;
    float4 v0 = *(const float4*)src;
    float4 v1 = *(const float4*)(src + 4);
    float fv[8] = {v0.x,v0.y,v0.z,v0.w,v1.x,v1.y,v1.z,v1.w};
    short8 out;
    #pragma unroll
    for(int j=0;j<8;j++) out[j] = (short)(__float_as_uint(fv[j]) >> 16);
    *(short8*)(img1 + (size_t)tid*16) = out;
  } else if(h < 1664){
    const int hb = h - 1536;
    const int b = hb >> 2, oc = hb & 3;
    kl[t] = *(const float4*)(kin + b*DIM + t*4);
    __syncthreads();
    const int o = oc*256 + t;
    const float4* wrow = (const float4*)(wa + (size_t)o*DIM);
    float acc = 0.f;
    for(int i=0;i<256;i++){
      float4 wv = wrow[i]; float4 kk = kl[i];
      acc += wv.x*kk.x + wv.y*kk.y + wv.z*kk.z + wv.w*kk.w;
    }
    avec[b*DIM + o] = acc;
  } else {
    // ---- stable compaction of unmasked rows for batch b ----
    const int b = h - 1664;
    int mv[8]; int c = 0;
    #pragma unroll
    for(int e=0;e<8;e++){ mv[e] = mask[b*NS + t*8 + e]; c += (mv[e] ? 1 : 0); }
    tc[t] = c;
    __syncthreads();
    for(int d=1; d<256; d<<=1){          // Hillis-Steele inclusive scan
      int v = tc[t];
      int add = (t >= d) ? tc[t-d] : 0;
      __syncthreads();
      tc[t] = v + add;
      __syncthreads();
    }
    const int excl = tc[t] - c;
    if(t == 255) tot = tc[t];
    __syncthreads();
    int pos = excl;
    #pragma unroll
    for(int e=0;e<8;e++){
      if(mv[e]) cidx[b*NS + (pos++)] = t*8 + e;
    }
    const int total = tot;
    if(t == 0) cnt[b] = total;
    for(int p = total + t; p < NS; p += 256) cidx[b*NS + p] = 0;  // safe pad
  }
}

// ---------------- phase-1: 1-pass truncated-bf16 GEMM over COMPACTED rows -----
// R9/R11-verified structure + R12 dense remap. R13 delta: XCD mapping is
// round-robin-aware (XCD = h%8): the 4 cb-blocks of a (batch,tile) pair sit at
// h == const (mod 8) and adjacent slots -> same XCD, A-panel fetched once.
__global__ __launch_bounds__(256,2)
void k_gemm_approx(const float* __restrict__ xs,
                   const char* __restrict__ img1,
                   const float* __restrict__ avec,
                   const float* __restrict__ energy,
                   const int* __restrict__ cidx,
                   const int* __restrict__ cnt,
                   float* __restrict__ partial){
  __shared__ us16 Abuf[128][40];      // hi only; row stride 80B
  __shared__ us16 Bbuf[2][128][64];   // 2 x 16KB, filled by global_load_lds

  const int h = blockIdx.x;                   // 2048 blocks
  int bidx, tile, cb;
  if(h < 1152){                               // dense: 32 b x 9 t x 4 cb
    const int q = h >> 3;                     // 0..143
    cb = q & 3;
    const int pair = (h & 7)*36 + (q >> 2);   // XCD h%8 owns pairs [36x,36x+36)
    bidx = pair / 9; tile = pair % 9;
  } else {                                    // rare region: tiles 9..15
    const int h2 = h - 1152;
    bidx = h2 / 28; tile = 9 + ((h2 % 28) >> 2); cb = h2 & 3;
  }
  if(tile*128 >= cnt[bidx]) return;           // tile beyond unmasked count
  const int t  = threadIdx.x;
  const int w  = t >> 6, lane = t & 63;
  const int wr = w >> 1, wc = w & 1;          // wave tile: 64 rows x 128 cols
  const int lm = lane & 15, lk = lane >> 4;
  const int sr = t >> 1, sh = t & 1;

  const int orig = cidx[bidx*NS + tile*128 + sr];   // gathered source row
  const float* ap = xs + ((size_t)bidx*NS + orig)*DIM + sh*16;
  const char*  bsrc = img1;                   // + (kt*4+cb)*16384

  const char* a_rd = (const char*)&Abuf[0][0] + (wr*64 + lm)*80 + ((lk*16) ^ ((lm&3)<<4));
  const int boff = (wc*64 + lk*16) ^ ((lm&7)<<4);

  f32x4 acc[4][8];
  #pragma unroll
  for(int m=0;m<4;m++)
    #pragma unroll
    for(int n=0;n<8;n++) acc[m][n] = (f32x4){0.f,0.f,0.f,0.f};

  // prologue: A(0) regs FIRST (oldest in FIFO), then B(0) gloads
  float4 ar0 = *(const float4*)(ap+0),  ar1 = *(const float4*)(ap+4);
  float4 ar2 = *(const float4*)(ap+8),  ar3 = *(const float4*)(ap+12);
  {
    const char* gs = bsrc + (size_t)cb*16384 + t*16;
    char* ld = (char*)&Bbuf[0][0][0] + t*16;
    #pragma unroll
    for(int c=0;c<4;c++) gload16(gs + c*4096, ld + c*4096);
  }

  for(int kt=0; kt<32; kt++){
    const int cur = kt & 1;
    // bar1: all waves' frag reads of tile kt-1 done (lgkm only — NO vmem drain)
    asm volatile("s_waitcnt lgkmcnt(0)" ::: "memory");
    __builtin_amdgcn_sched_barrier(0);
    __builtin_amdgcn_s_barrier();
    {   // truncate-store A(kt) from ar
      float fv[16];
      *(float4*)(fv+0)=ar0; *(float4*)(fv+4)=ar1;
      *(float4*)(fv+8)=ar2; *(float4*)(fv+12)=ar3;
      short8 h0, h1;
      #pragma unroll
      for(int j=0;j<8;j++){ h0[j] = (short)(__float_as_uint(fv[j])>>16);
                            h1[j] = (short)(__float_as_uint(fv[8+j])>>16); }
      char* abase = (char*)&Abuf[0][0] + sr*80;
      const int swz = (sr & 3) << 4;
      *(short8*)(abase + ((sh*32     ) ^ swz)) = h0;
      *(short8*)(abase + ((sh*32 + 16) ^ swz)) = h1;
    }
    if(kt < 31){
      const float* a2 = ap + (kt+1)*32;   // A(kt+1) regs first (oldest)
      ar0 = *(const float4*)(a2+0);  ar1 = *(const float4*)(a2+4);
      ar2 = *(const float4*)(a2+8);  ar3 = *(const float4*)(a2+12);
      {                                   // then B(kt+1) gloads
        const char* gs = bsrc + (size_t)((kt+1)*4 + cb)*16384 + t*16;
        char* ld = (char*)&Bbuf[cur^1][0][0] + t*16;
        #pragma unroll
        for(int c=0;c<4;c++) gload16(gs + c*4096, ld + c*4096);
      }
      // FIFO: [B(kt)4, A(kt+1)4, B(kt+1)4] -> vmcnt(8): B(kt) landed,
      // next-tile loads stay in flight. lgkm(0) = A ds_writes visible.
      asm volatile("s_waitcnt vmcnt(8) lgkmcnt(0)" ::: "memory");
    } else {
      asm volatile("s_waitcnt vmcnt(0) lgkmcnt(0)" ::: "memory");
    }
    __builtin_amdgcn_sched_barrier(0);
    __builtin_amdgcn_s_barrier();       // bar2: tile kt fully in LDS

    short8 fa[4], fb[8];
    const char* bb = (const char*)&Bbuf[cur][0][0] + lm*128 + boff;
    #pragma unroll
    for(int m=0;m<4;m++) fa[m] = *(const short8*)(a_rd + m*1280);
    #pragma unroll
    for(int n=0;n<8;n++) fb[n] = *(const short8*)(bb + n*2048);
    #pragma unroll
    for(int m=0;m<4;m++)
      #pragma unroll
      for(int n=0;n<8;n++)
        acc[m][n] = __builtin_amdgcn_mfma_f32_16x16x32_bf16(fa[m], fb[n], acc[m][n], 0,0,0);
  }

  // epilogue: partial[cb*2+wc][compacted row] over wave's 128 cols
  float av[8], ev[8];
  #pragma unroll
  for(int n=0;n<8;n++){
    const int col = cb*256 + wc*128 + n*16 + lm;
    av[n] = avec[bidx*DIM + col];
    ev[n] = energy[col];
  }
  #pragma unroll
  for(int m=0;m<4;m++){
    float rs[4];
    #pragma unroll
    for(int j=0;j<4;j++){
      float s = 0.f;
      #pragma unroll
      for(int n=0;n<8;n++) s += ev[n]*fast_tanh(av[n] + acc[m][n][j]);
      s += __shfl_xor(s,1); s += __shfl_xor(s,2);
      s += __shfl_xor(s,4); s += __shfl_xor(s,8);
      rs[j] = s;
    }
    if(lm == 0){
      float4 st = {rs[0], rs[1], rs[2], rs[3]};
      *(float4*)(partial + (size_t)(cb*2+wc)*NM + bidx*NS + tile*128 + wr*64 + m*16 + lk*4) = st;
    }
  }
}

// ---------------- select over compacted rows; scatter scores to orig ids ------
__global__ void k_select(const float* __restrict__ partial,
                         const int* __restrict__ cidx,
                         const int* __restrict__ cnt,
                         float* __restrict__ scores,
                         int* __restrict__ sel_count,
                         int* __restrict__ sel_list){
  const int b = blockIdx.x, t = threadIdx.x;
  const int w = t >> 6, lane = t & 63;
  __shared__ float red[4];
  const int cnt_b = cnt[b];
  float sv[8]; int orig[8];
  float m = -3.4e38f;
  #pragma unroll
  for(int j=0;j<8;j++){
    const int i = j*256 + t;                  // compacted index
    if(i < cnt_b){
      float s = 0.f;
      #pragma unroll
      for(int c=0;c<8;c++) s += partial[(size_t)c*NM + b*NS + i];
      sv[j] = s;
      orig[j] = cidx[b*NS + i];
      scores[b*NS + orig[j]] = s;             // all compacted rows are unmasked
      if(s > m) m = s;
    } else { sv[j] = -3.4e38f; orig[j] = -1; }
  }
  #pragma unroll
  for(int off=1; off<64; off<<=1) m = fmaxf(m, __shfl_xor(m, off));
  if(lane==0) red[w] = m;
  __syncthreads();
  m = fmaxf(fmaxf(red[0],red[1]), fmaxf(red[2],red[3]));
  const float thr = m - SEL_MARGIN;
  #pragma unroll
  for(int j=0;j<8;j++){
    if(orig[j] >= 0 && sv[j] > thr){
      int slot = atomicAdd(&sel_count[b], 1);
      if(slot < CAP) sel_list[b*CAP + slot] = orig[j];
    }
  }
}

// ---------------- phase-2: exact 3-pass rescoring of selected rows ------------
__global__ __launch_bounds__(256)
void k_phase2(const float* __restrict__ xs,
              const char* __restrict__ imgf,
              const float* __restrict__ avec,
              const float* __restrict__ energy,
              const int* __restrict__ sel_count,
              const int* __restrict__ sel_list,
              float* __restrict__ p2buf){
  __shared__ us16 A2[32][80];     // hi bytes [0,64), lo at +80, row stride 160B
  __shared__ float s2[4][32];
  const int b = blockIdx.x >> 4, cb = blockIdx.x & 15;
  const int t = threadIdx.x, w = t >> 6, lane = t & 63;
  const int lm = lane & 15, lk = lane >> 4;
  const int ct = cb*4 + w;                    // ct16 index 0..63
  const int col = ct*16 + lm;
  const float av  = avec[b*DIM + col];
  const float evv = energy[col];
  char* lds = (char*)&A2[0][0];
  const int count = min(sel_count[b], CAP);
  const int ri = t >> 3, seg = t & 7;
  // 2-bit XOR key: must stay inside the 64-byte hi field (R6 lesson)
  const int wbyte = ri*160 + ((seg*8) ^ ((ri&3)<<4));
  const char* a_rd = lds + lm*160 + ((lk*16) ^ ((lm&3)<<4));

  for(int c0 = 0; c0 < count; c0 += 32){
    const int li = c0 + ri;
    const int row = sel_list[b*CAP + min(li, count-1)];
    const float* rp = xs + ((size_t)b*NS + row)*DIM + seg*4;
    f32x4 acc[2];
    acc[0] = (f32x4){0.f,0.f,0.f,0.f};
    acc[1] = (f32x4){0.f,0.f,0.f,0.f};
    for(int kt=0; kt<32; kt++){
      __syncthreads();                        // prior kt's frag reads consumed
      float4 v = *(const float4*)(rp + kt*32);
      float fv[4] = {v.x, v.y, v.z, v.w};
      us16x4 hi, lo;
      #pragma unroll
      for(int e=0;e<4;e++){
        short a, l; split_bf16(fv[e], a, l);
        hi[e] = (us16)a; lo[e] = (us16)l;
      }
      *(us16x4*)(lds + wbyte)      = hi;
      *(us16x4*)(lds + wbyte + 80) = lo;
      __syncthreads();
      const char* fbb = imgf + ((size_t)(kt*64 + ct)*2)*1024 + lane*16;
      short8 bh = *(const short8*)(fbb);
      short8 bl = *(const short8*)(fbb + 1024);
      short8 fah[2], fal[2];
      #pragma unroll
      for(int m=0;m<2;m++){
        fah[m] = *(const short8*)(a_rd + m*2560);
        fal[m] = *(const short8*)(a_rd + m*2560 + 80);
      }
      #pragma unroll
      for(int m=0;m<2;m++)
        acc[m] = __builtin_amdgcn_mfma_f32_16x16x32_bf16(fah[m], bh, acc[m], 0,0,0);
      #pragma unroll
      for(int m=0;m<2;m++)
        acc[m] = __builtin_amdgcn_mfma_f32_16x16x32_bf16(fah[m], bl, acc[m], 0,0,0);
      #pragma unroll
      for(int m=0;m<2;m++)
        acc[m] = __builtin_amdgcn_mfma_f32_16x16x32_bf16(fal[m], bh, acc[m], 0,0,0);
    }
    float s[2][4];
    #pragma unroll
    for(int m=0;m<2;m++)
      #pragma unroll
      for(int j=0;j<4;j++){
        float v = evv * fast_tanh(av + acc[m][j]);
        v += __shfl_xor(v,1); v += __shfl_xor(v,2);
        v += __shfl_xor(v,4); v += __shfl_xor(v,8);
        s[m][j] = v;
      }
    __syncthreads();
    if(lm == 0){
      #pragma unroll
      for(int m=0;m<2;m++)
        #pragma unroll
        for(int j=0;j<4;j++) s2[w][m*16 + lk*4 + j] = s[m][j];
    }
    __syncthreads();
    if(t < 32){
      float sum = s2[0][t] + s2[1][t] + s2[2][t] + s2[3][t];
      p2buf[((size_t)b*16 + cb)*CAP + c0 + t] = sum;
    }
  }
}

// ------ masked softmax + exact-score scatter + deterministic significant list -
__global__ void k_softmax(const float* __restrict__ scores,
                          const float* __restrict__ p2buf,
                          const int* __restrict__ sel_count,
                          const int* __restrict__ sel_list,
                          const int* __restrict__ mask,
                          float* __restrict__ attn,
                          int* __restrict__ slist2,
                          float* __restrict__ sval2,
                          int* __restrict__ scount2){
  const int b = blockIdx.x, t = threadIdx.x;
  const int w = t >> 6, lane = t & 63;
  __shared__ float sc[NS];      // 8KB: corrected scores
  __shared__ float red[4];
  __shared__ int tc[256];
  __shared__ int tot;
  #pragma unroll
  for(int j=0;j<8;j++) sc[j*256+t] = scores[b*NS + j*256 + t];
  __syncthreads();
  const int count = min(sel_count[b], CAP);
  for(int s0 = t; s0 < count; s0 += 256){
    float s = 0.f;
    #pragma unroll
    for(int c=0;c<16;c++) s += p2buf[((size_t)b*16 + c)*CAP + s0];
    sc[sel_list[b*CAP + s0]] = s;
  }
  __syncthreads();
  float sv[8]; int mv[8];
  float m = -3.4e38f;
  #pragma unroll
  for(int j=0;j<8;j++){
    const int i = j*256 + t;
    sv[j] = sc[i];
    mv[j] = mask[b*NS + i];
    if(mv[j] && sv[j] > m) m = sv[j];
  }
  #pragma unroll
  for(int off=1; off<64; off<<=1) m = fmaxf(m, __shfl_xor(m, off));
  if(lane==0) red[w] = m;
  __syncthreads();
  m = fmaxf(fmaxf(red[0],red[1]), fmaxf(red[2],red[3]));
  __syncthreads();
  float ev[8]; float l = 0.f;
  #pragma unroll
  for(int j=0;j<8;j++){
    ev[j] = mv[j] ? __builtin_exp2f((sv[j]-m)*1.4426950408889634f) : 0.f;
    l += ev[j];
  }
  #pragma unroll
  for(int off=1; off<64; off<<=1) l += __shfl_xor(l, off);
  if(lane==0) red[w] = l;
  __syncthreads();
  l = red[0]+red[1]+red[2]+red[3];
  const float inv = 1.0f/l;
  // write attn + deterministic ordered list of significant rows (attn > 1e-9)
  float av8[8]; int sig[8]; int c = 0;
  #pragma unroll
  for(int j=0;j<8;j++){
    av8[j] = ev[j]*inv;
    attn[b*NS + j*256 + t] = av8[j];
    sig[j] = (av8[j] > 1e-9f) ? 1 : 0;
    c += sig[j];
  }
  tc[t] = c;
  __syncthreads();
  for(int d=1; d<256; d<<=1){            // Hillis-Steele inclusive scan
    int v = tc[t];
    int add = (t >= d) ? tc[t-d] : 0;
    __syncthreads();
    tc[t] = v + add;
    __syncthreads();
  }
  const int excl = tc[t] - c;
  if(t == 255) tot = tc[t];
  __syncthreads();
  int pos = excl;
  #pragma unroll
  for(int j=0;j<8;j++){
    if(sig[j]){
      slist2[b*NS + pos] = j*256 + t;
      sval2 [b*NS + pos] = av8[j];
      pos++;
    }
  }
  if(t == 0) scount2[b] = tot;
}

// ---------------- ctx = sum over significant rows (deterministic order) -------
__global__ void k_ctx(const int* __restrict__ slist2,
                      const float* __restrict__ sval2,
                      const int* __restrict__ scount2,
                      const float* __restrict__ xs,
                      float* __restrict__ ctx){
  const int b = blockIdx.x, t = threadIdx.x;
  __shared__ int   rows[NS];    // 8KB
  __shared__ float aw[NS];      // 8KB
  const int n = scount2[b];
  for(int i = t; i < n; i += 256){
    rows[i] = slist2[b*NS + i];
    aw[i]   = sval2 [b*NS + i];
  }
  __syncthreads();
  float4 acc = {0.f,0.f,0.f,0.f};
  const float* xb = xs + (size_t)b*NS*DIM + t*4;
  for(int j=0;j<n;j++){
    const float wv = aw[j];
    const float4 x = *(const float4*)(xb + (size_t)rows[j]*DIM);
    acc.x += wv*x.x; acc.y += wv*x.y; acc.z += wv*x.z; acc.w += wv*x.w;
  }
  *(float4*)(ctx + b*DIM + t*4) = acc;
}

extern "C" void kernel_launch(void* const* d_in, const int* in_sizes, int n_in,
                              void* d_out, int out_size, void* d_ws, size_t ws_size,
                              hipStream_t stream) {
  const float* kin    = (const float*)d_in[0];   // [32,1024]
  const float* xs     = (const float*)d_in[1];   // [32,2048,1024]
  const int*   mask   = (const int*)d_in[2];     // [32,2048]
  const float* wa     = (const float*)d_in[3];   // [1024,1024]
  const float* wb     = (const float*)d_in[4];   // [1024,1024]
  const float* energy = (const float*)d_in[5];   // [1024]
  float* out  = (float*)d_out;
  float* ctx  = out;            // [32,1024]
  float* attn = out + NB*DIM;   // [32,2048]

  char* ws = (char*)d_ws;
  float* partial   = (float*)(ws);                       // 2 MB    @ 0
  float* avec      = (float*)(ws + 2097152);             // 128 KB
  float* scores    = (float*)(ws + 2228224);             // 256 KB
  int*   slist2    = (int*)(ws + 2490368);               // 256 KB
  float* sval2     = (float*)(ws + 2752512);             // 256 KB
  int*   scount2   = (int*)(ws + 3014656);               // 128 B
  char*  imgf      = ws + 3538944;                       // 4 MB (frag hi/lo)
  char*  img1      = ws + 7733248;                       // 2 MB (gload hi, BK=32)
  int*   sel_count = (int*)(ws + 9830400);               // 128 B
  int*   sel_list  = (int*)(ws + 9830528);               // 32 KB
  float* p2buf     = (float*)(ws + 9863296);             // 512 KB
  int*   cidx      = (int*)(ws + 10387584);              // 256 KB
  int*   cnt       = (int*)(ws + 10649728);              // 128 B

  k_prep       <<<1696, 256, 0, stream>>>(wb, kin, wa, mask, imgf, img1, avec,
                                          cidx, cnt, sel_count);
  k_gemm_approx<<<2048, 256, 0, stream>>>(xs, img1, avec, energy, cidx, cnt, partial);
  k_select     <<<NB, 256, 0, stream>>>(partial, cidx, cnt, scores, sel_count, sel_list);
  k_phase2     <<<512, 256, 0, stream>>>(xs, imgf, avec, energy, sel_count, sel_list, p2buf);
  k_softmax    <<<NB, 256, 0, stream>>>(scores, p2buf, sel_count, sel_list, mask, attn,
                                        slist2, sval2, scount2);
  k_ctx        <<<NB, 256, 0, stream>>>(slist2, sval2, scount2, xs, ctx);
}